// Round 1
// baseline (1731.761 us; speedup 1.0000x reference)
//
#include <hip/hip_runtime.h>
#include <math.h>

#define BB 256
#define TT 16
#define CC 40
#define HH 4
#define DD 10
#define VV 50257
#define ROWS (BB*TT)            // 4096
#define S_CHUNKS 8
#define CHUNK ((VV + S_CHUNKS - 1) / S_CHUNKS)   // 6283

// ---------------- Kernel 1: embeddings + attention -> out_rows[4096][40] ----
__global__ __launch_bounds__(64) void attn_kernel(
    const int* __restrict__ idx, const float* __restrict__ tok_emb,
    const float* __restrict__ pos_emb, const float* __restrict__ Wq,
    const float* __restrict__ Wk, const float* __restrict__ Wv,
    float* __restrict__ out_rows)
{
    __shared__ float xs[TT][CC];
    __shared__ float qs[HH][TT][DD], ks[HH][TT][DD], vs2[HH][TT][DD];
    const int b = blockIdx.x;
    const int tid = threadIdx.x;

    for (int i = tid; i < TT*CC; i += 64) {
        int t = i / CC, c = i % CC;
        int tok = idx[b*TT + t];
        xs[t][c] = tok_emb[tok*CC + c] + pos_emb[t*CC + c];   // pos = t % 16 = t
    }
    __syncthreads();

    const int h = tid >> 4, t = tid & 15;
    float qd[DD], kd[DD], vd[DD];
    #pragma unroll
    for (int d = 0; d < DD; ++d) { qd[d] = 0.f; kd[d] = 0.f; vd[d] = 0.f; }
    for (int c = 0; c < CC; ++c) {
        float xv = xs[t][c];
        int base = h*CC*DD + c*DD;
        #pragma unroll
        for (int d = 0; d < DD; ++d) {
            qd[d] += xv * Wq[base + d];
            kd[d] += xv * Wk[base + d];
            vd[d] += xv * Wv[base + d];
        }
    }
    #pragma unroll
    for (int d = 0; d < DD; ++d) { qs[h][t][d] = qd[d]; ks[h][t][d] = kd[d]; vs2[h][t][d] = vd[d]; }
    __syncthreads();

    // causal scores over s <= t, NO 1/sqrt(d) scaling (faithful to reference)
    float sc[TT];
    float m = -1e30f;
    for (int s = 0; s <= t; ++s) {
        float a = 0.f;
        #pragma unroll
        for (int d = 0; d < DD; ++d) a += qd[d] * ks[h][s][d];
        sc[s] = a;
        m = fmaxf(m, a);
    }
    float z = 0.f;
    for (int s = 0; s <= t; ++s) { sc[s] = __expf(sc[s] - m); z += sc[s]; }
    float inv = 1.0f / z;
    float od[DD];
    #pragma unroll
    for (int d = 0; d < DD; ++d) od[d] = 0.f;
    for (int s = 0; s <= t; ++s) {
        float p = sc[s] * inv;
        #pragma unroll
        for (int d = 0; d < DD; ++d) od[d] += p * vs2[h][s][d];
    }
    const int row = b*TT + t;
    #pragma unroll
    for (int d = 0; d < DD; ++d) out_rows[row*CC + h*DD + d] = od[d];
}

// ---------------- Kernel 2: logits + fused partial sum-exp ------------------
// grid = (ROWS/16) * S_CHUNKS blocks; block owns 16 rows x one V-chunk.
// blockIdx % 8 = chunk (XCD round-robin heuristic -> chunk's 1MB B-slice stays
// in one XCD's L2). Logits tiny (|x|<~0.3) so sum-exp needs no max shift.
__global__ __launch_bounds__(256) void logits_kernel(
    const float* __restrict__ out_rows, const float* __restrict__ lm_W,
    const float* __restrict__ lm_b, float* __restrict__ logits,
    float* __restrict__ partials)
{
    __shared__ float outT[CC][16];     // [c][r] transposed, rows of 16 floats (64B)
    __shared__ float red[16][4];
    const int sidx = blockIdx.x & (S_CHUNKS - 1);
    const int g    = blockIdx.x >> 3;
    const int tid  = threadIdx.x;
    const int r0   = g * 16;

    for (int i = tid; i < 16*CC; i += 256) {
        int r = i / CC, c = i % CC;
        outT[c][r] = out_rows[(r0 + r)*CC + c];
    }
    __syncthreads();

    const int vs = sidx * CHUNK;
    const int ve = min(VV, vs + CHUNK);

    float sumexp[16];
    #pragma unroll
    for (int r = 0; r < 16; ++r) sumexp[r] = 0.f;

    for (int va = vs + tid; va < ve; va += 512) {
        const int vb = va + 256;
        const bool hb = (vb < ve);
        const int vbs = hb ? vb : va;          // safe address when out of range
        float accA[16], accB[16];
        #pragma unroll
        for (int r = 0; r < 16; ++r) { accA[r] = 0.f; accB[r] = 0.f; }
        const float* wp = lm_W;
        #pragma unroll 8
        for (int c = 0; c < CC; ++c) {
            const float bA = wp[va];
            const float bB = wp[vbs];
            const float4* xt = reinterpret_cast<const float4*>(&outT[c][0]);
            float4 x0 = xt[0], x1 = xt[1], x2 = xt[2], x3 = xt[3];
            accA[0]  += x0.x*bA; accA[1]  += x0.y*bA; accA[2]  += x0.z*bA; accA[3]  += x0.w*bA;
            accA[4]  += x1.x*bA; accA[5]  += x1.y*bA; accA[6]  += x1.z*bA; accA[7]  += x1.w*bA;
            accA[8]  += x2.x*bA; accA[9]  += x2.y*bA; accA[10] += x2.z*bA; accA[11] += x2.w*bA;
            accA[12] += x3.x*bA; accA[13] += x3.y*bA; accA[14] += x3.z*bA; accA[15] += x3.w*bA;
            accB[0]  += x0.x*bB; accB[1]  += x0.y*bB; accB[2]  += x0.z*bB; accB[3]  += x0.w*bB;
            accB[4]  += x1.x*bB; accB[5]  += x1.y*bB; accB[6]  += x1.z*bB; accB[7]  += x1.w*bB;
            accB[8]  += x2.x*bB; accB[9]  += x2.y*bB; accB[10] += x2.z*bB; accB[11] += x2.w*bB;
            accB[12] += x3.x*bB; accB[13] += x3.y*bB; accB[14] += x3.z*bB; accB[15] += x3.w*bB;
            wp += VV;
        }
        const float biasA = lm_b[va];
        const float biasB = lm_b[vbs];
        #pragma unroll
        for (int r = 0; r < 16; ++r) {
            float la = accA[r] + biasA;
            logits[(size_t)(r0 + r)*VV + va] = la;
            sumexp[r] += __expf(la);
            if (hb) {
                float lb = accB[r] + biasB;
                logits[(size_t)(r0 + r)*VV + vb] = lb;
                sumexp[r] += __expf(lb);
            }
        }
    }

    // reduce per-row sum-exp across the 4 waves
    const int lane = tid & 63, wv = tid >> 6;
    #pragma unroll
    for (int r = 0; r < 16; ++r) {
        float sv = sumexp[r];
        for (int off = 32; off > 0; off >>= 1) sv += __shfl_down(sv, off);
        if (lane == 0) red[r][wv] = sv;
    }
    __syncthreads();
    if (tid < 16) {
        float zz = red[tid][0] + red[tid][1] + red[tid][2] + red[tid][3];
        partials[(r0 + tid)*S_CHUNKS + sidx] = zz;
    }
}

// ---------------- Kernel 3: loss ------------------------------------------
__global__ __launch_bounds__(256) void loss_kernel(
    const int* __restrict__ targets, const float* __restrict__ out_rows,
    const float* __restrict__ lm_W, const float* __restrict__ lm_b,
    const float* __restrict__ partials, float* __restrict__ loss_out)
{
    __shared__ float red[256];
    const int tid = threadIdx.x;
    float acc = 0.f;
    for (int r = tid; r < ROWS; r += 256) {
        int tgt = targets[r];
        float lt = lm_b[tgt];
        #pragma unroll
        for (int c = 0; c < CC; ++c) lt += out_rows[r*CC + c] * lm_W[c*VV + tgt];
        float z = 0.f;
        #pragma unroll
        for (int s = 0; s < S_CHUNKS; ++s) z += partials[r*S_CHUNKS + s];
        acc += logf(z) - lt;      // -(logit_t - logsumexp)
    }
    red[tid] = acc;
    __syncthreads();
    for (int off = 128; off > 0; off >>= 1) {
        if (tid < off) red[tid] += red[tid + off];
        __syncthreads();
    }
    if (tid == 0) loss_out[0] = red[0] / (float)ROWS;
}

// ---------------- launch ---------------------------------------------------
extern "C" void kernel_launch(void* const* d_in, const int* in_sizes, int n_in,
                              void* d_out, int out_size, void* d_ws, size_t ws_size,
                              hipStream_t stream) {
    const int*   idx     = (const int*)d_in[0];
    const int*   targets = (const int*)d_in[1];
    const float* tok_emb = (const float*)d_in[2];
    const float* pos_emb = (const float*)d_in[3];
    const float* Wq      = (const float*)d_in[4];
    const float* Wk      = (const float*)d_in[5];
    const float* Wv      = (const float*)d_in[6];
    const float* lm_W    = (const float*)d_in[7];
    const float* lm_b    = (const float*)d_in[8];

    float* logits   = (float*)d_out;
    float* loss_out = logits + (size_t)ROWS * VV;   // last element of d_out
    float* out_rows = (float*)d_ws;                 // 4096*40 fp32
    float* partials = out_rows + ROWS*CC;           // 4096*8  fp32

    attn_kernel<<<BB, 64, 0, stream>>>(idx, tok_emb, pos_emb, Wq, Wk, Wv, out_rows);
    logits_kernel<<<(ROWS/16)*S_CHUNKS, 256, 0, stream>>>(out_rows, lm_W, lm_b, logits, partials);
    loss_kernel<<<1, 256, 0, stream>>>(targets, out_rows, lm_W, lm_b, partials, loss_out);
}